// Round 3
// baseline (239.112 us; speedup 1.0000x reference)
//
#include <hip/hip_runtime.h>
#include <math.h>

#define NB 8
#define NQ 128
#define NK 1024
#define ND 512   // QK_DIM
#define NH 256   // HID
#define NV 512   // VDIM

typedef __attribute__((ext_vector_type(8))) short short8v;   // 8 bf16
typedef __attribute__((ext_vector_type(4))) float floatx4;

// ---------- bf16 helpers (RNE) ----------
__device__ __forceinline__ ushort f2bf(float f) {
  union { float f; unsigned u; } v; v.f = f;
  unsigned r = (v.u + 0x7FFF + ((v.u >> 16) & 1)) >> 16;
  return (ushort)r;
}
__device__ __forceinline__ float bf2f(ushort b) {
  union { unsigned u; float f; } v; v.u = ((unsigned)b) << 16;
  return v.f;
}

__device__ __forceinline__ float wave_rsum(float v) {
#pragma unroll
  for (int off = 32; off; off >>= 1) v += __shfl_xor(v, off);
  return v;
}
__device__ __forceinline__ float wave_rmin(float v) {
#pragma unroll
  for (int off = 32; off; off >>= 1) v = fminf(v, __shfl_xor(v, off));
  return v;
}

// =====================================================================
// K0: W [ND][NH] f32  ->  Wt hi/lo [NH][ND] bf16 (transposed + split).
// 256 blocks (128 per matrix), 32x32 tiles via LDS.
// =====================================================================
__global__ __launch_bounds__(256) void splitw_kernel(
    const float* __restrict__ Wq, const float* __restrict__ Wk,
    ushort* __restrict__ WtQh, ushort* __restrict__ WtQl,
    ushort* __restrict__ WtKh, ushort* __restrict__ WtKl) {
  const int t = threadIdx.x;
  const int mat = blockIdx.x >> 7;
  const int bi = blockIdx.x & 127;            // 16 d-tiles x 8 h-tiles
  const int d0 = (bi >> 3) * 32, h0 = (bi & 7) * 32;
  const float* W = mat ? Wk : Wq;
  ushort* Oh = mat ? WtKh : WtQh;
  ushort* Ol = mat ? WtKl : WtQl;
  __shared__ float tile[32][33];
#pragma unroll
  for (int i = 0; i < 4; ++i) {
    int idx = t + 256 * i;
    int r = idx >> 5, c = idx & 31;           // r: d, c: h (coalesced h)
    tile[r][c] = W[(size_t)(d0 + r) * NH + h0 + c];
  }
  __syncthreads();
#pragma unroll
  for (int i = 0; i < 4; ++i) {
    int idx = t + 256 * i;
    int hh = idx >> 5, dd = idx & 31;         // out row h, col d (coalesced d)
    float f = tile[dd][hh];
    ushort hi = f2bf(f);
    float lo = f - bf2f(hi);
    Oh[(size_t)(h0 + hh) * ND + d0 + dd] = hi;
    Ol[(size_t)(h0 + hh) * ND + d0 + dd] = f2bf(lo);
  }
}

// =====================================================================
// K1: projection via split-bf16 MFMA + exp2 epilogue.
// C = A @ W with A split hi/lo in-kernel, W pre-split (K0).
// acc = Ahi*Whi + Ahi*Wlo + Alo*Whi  (~f32 precision).
// Block = 16 rows x 256 cols, 4 waves (each 16x64 via 4 16x16 frags).
// grid 576: bx<64 -> q row-tiles -> Eq[row][h] f32;
//           bx>=64 -> k row-tiles -> EkT[b][h][k] bf16 (k-tiles >= V skip).
// MFMA 16x16x32_bf16; A-frag: lane holds A[l&15][(l>>4)*8+j] (16B contig);
// B-frag: Wt[col=l&15 offset][(l>>4)*8+j]; C/D: col=l&15, row=(l>>4)*4+reg
// (verified layout).
// =====================================================================
__global__ __launch_bounds__(256) void proj_mfma_kernel(
    const float* __restrict__ queries, const float* __restrict__ keys,
    const ushort* __restrict__ WtQh, const ushort* __restrict__ WtQl,
    const ushort* __restrict__ WtKh, const ushort* __restrict__ WtKl,
    const int* __restrict__ valid_lens,
    float* __restrict__ Eq, ushort* __restrict__ EkTb) {
  const int t = threadIdx.x;
  const int lane = t & 63;
  const int wvid = t >> 6;
  const int lr = lane & 15;     // A-row / B-col / C-col within frag
  const int lg = lane >> 4;     // k-group (A/B), row-group (C)
  const int bx = blockIdx.x;
  const bool isQ = bx < 64;
  const float* A;
  const ushort *Wh, *Wl;
  int arow0, b = 0, rin = 0;
  if (isQ) {
    A = queries; Wh = WtQh; Wl = WtQl; arow0 = bx * 16;
  } else {
    int kt = bx - 64;                // 0..511
    b = kt >> 6; rin = (kt & 63) * 16;
    if (rin >= valid_lens[b]) return;
    A = keys; Wh = WtKh; Wl = WtKl; arow0 = b * NK + rin;
  }
  const size_t arow = (size_t)(arow0 + lr) * ND;
  const int c0w = wvid * 64;

  floatx4 acc[4];
#pragma unroll
  for (int cf = 0; cf < 4; ++cf) acc[cf] = (floatx4){0.f, 0.f, 0.f, 0.f};

#pragma unroll 4
  for (int kk = 0; kk < 16; ++kk) {
    const int d0 = kk * 32 + lg * 8;
    float4 a0 = *(const float4*)&A[arow + d0];
    float4 a1 = *(const float4*)&A[arow + d0 + 4];
    float av[8] = {a0.x, a0.y, a0.z, a0.w, a1.x, a1.y, a1.z, a1.w};
    short8v ah, al;
#pragma unroll
    for (int j = 0; j < 8; ++j) {
      ushort h = f2bf(av[j]);
      ah[j] = (short)h;
      al[j] = (short)f2bf(av[j] - bf2f(h));
    }
#pragma unroll
    for (int cf = 0; cf < 4; ++cf) {
      const size_t wrow = (size_t)(c0w + cf * 16 + lr) * ND + d0;
      short8v bh = *(const short8v*)&Wh[wrow];
      short8v bl = *(const short8v*)&Wl[wrow];
      acc[cf] = __builtin_amdgcn_mfma_f32_16x16x32_bf16(al, bh, acc[cf], 0, 0, 0);
      acc[cf] = __builtin_amdgcn_mfma_f32_16x16x32_bf16(ah, bl, acc[cf], 0, 0, 0);
      acc[cf] = __builtin_amdgcn_mfma_f32_16x16x32_bf16(ah, bh, acc[cf], 0, 0, 0);
    }
  }

  const float C2 = 2.885390081777927f;  // 2*log2(e)
  if (isQ) {
#pragma unroll
    for (int cf = 0; cf < 4; ++cf) {
      const int h = c0w + cf * 16 + lr;
#pragma unroll
      for (int reg = 0; reg < 4; ++reg) {
        const int row = arow0 + lg * 4 + reg;
        float p = fminf(fmaxf(acc[cf][reg], -15.f), 15.f);
        Eq[(size_t)row * NH + h] = exp2f(p * C2);
      }
    }
  } else {
#pragma unroll
    for (int cf = 0; cf < 4; ++cf) {
      const int h = c0w + cf * 16 + lr;
      ushort4 e;
      {
        float p0 = fminf(fmaxf(acc[cf][0], -15.f), 15.f);
        float p1 = fminf(fmaxf(acc[cf][1], -15.f), 15.f);
        float p2 = fminf(fmaxf(acc[cf][2], -15.f), 15.f);
        float p3 = fminf(fmaxf(acc[cf][3], -15.f), 15.f);
        e.x = f2bf(exp2f(p0 * C2));
        e.y = f2bf(exp2f(p1 * C2));
        e.z = f2bf(exp2f(p2 * C2));
        e.w = f2bf(exp2f(p3 * C2));
      }
      *(ushort4*)&EkTb[((size_t)(b * NH + h)) * NK + rin + lg * 4] = e;
    }
  }
}

// =====================================================================
// K2: racc[b,q,k] = sum_h wv_h * rcp(1 + Eq[q,h]*Ek[k,h]).
// softmax(score) == softmax(-2*racc)  (sumW constant drops out).
// grid (64 q-pairs, 4 k-tiles, 8 b), 256 thr; thread = 1 k x 2 q.
// ~1300 alive blocks -> ~5 waves/SIMD.
// =====================================================================
__global__ __launch_bounds__(256) void score_kernel(
    const float* __restrict__ Eq, const ushort* __restrict__ EkTb,
    const float* __restrict__ wvp, const int* __restrict__ valid_lens,
    float* __restrict__ racc) {
  const int b = blockIdx.z;
  const int V = valid_lens[b];
  const int k0 = blockIdx.y * 256;
  if (k0 >= V) return;
  const int t = threadIdx.x;
  const int q0 = blockIdx.x * 2;

  __shared__ float eqs[2][NH];
  __shared__ float wvs[NH];
  for (int i = t; i < 2 * NH; i += 256)
    eqs[i >> 8][i & 255] = Eq[(size_t)(b * NQ + q0 + (i >> 8)) * NH + (i & 255)];
  wvs[t] = wvp[t];
  __syncthreads();

  const ushort* ek = EkTb + (size_t)b * NH * NK + k0 + t;
  float acc0 = 0.f, acc1 = 0.f;
#pragma unroll 8
  for (int h = 0; h < NH; ++h) {
    const float e = bf2f(ek[(size_t)h * NK]);
    const float w = wvs[h];
    acc0 += w * __builtin_amdgcn_rcpf(__builtin_fmaf(eqs[0][h], e, 1.f));
    acc1 += w * __builtin_amdgcn_rcpf(__builtin_fmaf(eqs[1][h], e, 1.f));
  }
  const int k = k0 + t;
  if (k < V) {
    racc[(size_t)(b * NQ + q0) * NK + k] = acc0;
    racc[(size_t)(b * NQ + q0 + 1) * NK + k] = acc1;
  }
}

// =====================================================================
// K2.5: per-row softmax stats over score = -2*racc.
// p = exp2(fma(racc, -2log2e, A0)), A0 = 2log2e * min(racc);
// store {A0, 1/sum(p)} per row. One wave per row, 256 blocks.
// =====================================================================
__global__ __launch_bounds__(256) void rowstats_kernel(
    const float* __restrict__ racc, const int* __restrict__ valid_lens,
    float2* __restrict__ rowstat) {
  const int row = blockIdx.x * 4 + (threadIdx.x >> 6);
  const int lane = threadIdx.x & 63;
  const int V = valid_lens[row >> 7];
  const float* r = racc + (size_t)row * NK;
  const float L2E2 = 2.8853900817779268f;  // 2*log2(e)

  float vals[16];
  float amin = 1e30f;
#pragma unroll
  for (int it = 0; it < 4; ++it) {
    const int kb = it * 256 + lane * 4;
    float4 f = *(const float4*)&r[kb];
    vals[it * 4 + 0] = f.x; vals[it * 4 + 1] = f.y;
    vals[it * 4 + 2] = f.z; vals[it * 4 + 3] = f.w;
#pragma unroll
    for (int e = 0; e < 4; ++e)
      if (kb + e < V) amin = fminf(amin, vals[it * 4 + e]);
  }
  amin = wave_rmin(amin);
  const float A0 = L2E2 * amin;
  float s = 0.f;
#pragma unroll
  for (int it = 0; it < 4; ++it) {
    const int kb = it * 256 + lane * 4;
#pragma unroll
    for (int e = 0; e < 4; ++e)
      if (kb + e < V) s += exp2f(__builtin_fmaf(vals[it * 4 + e], -L2E2, A0));
  }
  s = wave_rsum(s);
  if (lane == 0) rowstat[row] = make_float2(A0, __builtin_amdgcn_rcpf(s));
}

// =====================================================================
// K3: PV with k-split + f32 atomicAdd into zeroed out.
// grid (16 qt x 4 vq, 4 kt, 8 b), 256 thr. Block: 8 q rows, 128 v cols,
// 256 k. p recomputed from racc (normalized by 1/s), staged in 8KB LDS.
// Wave = 2 rows x 32 float4-cols; all 4 waves read identical values lines.
// =====================================================================
__global__ __launch_bounds__(256) void pv_kernel(
    const float* __restrict__ racc, const float* __restrict__ values,
    const float2* __restrict__ rowstat, const int* __restrict__ valid_lens,
    float* __restrict__ out) {
  const int qt = blockIdx.x >> 2;
  const int vq = blockIdx.x & 3;
  const int kt = blockIdx.y;
  const int b  = blockIdx.z;
  const int V  = valid_lens[b];
  const int k0 = kt * 256;
  if (k0 >= V) return;
  const int kcnt = min(256, V - k0);
  const int t = threadIdx.x;
  const int q0 = qt * 8;
  const float L2E2 = 2.8853900817779268f;

  __shared__ float p[8][256];
#pragma unroll
  for (int i = 0; i < 8; ++i) {
    const int row = b * NQ + q0 + i;
    const float2 st = rowstat[row];
    const float a = racc[(size_t)row * NK + k0 + t];
    p[i][t] = (t < kcnt) ? exp2f(__builtin_fmaf(a, -L2E2, st.x)) * st.y : 0.f;
  }
  __syncthreads();

  const int lane = t & 63, g = t >> 6;
  const int hi = lane >> 5, c4 = lane & 31;
  const int row = g * 2 + hi;
  const float* vb = values + (size_t)(b * NK + k0) * NV + vq * 128 + c4 * 4;
  float4 acc = {0.f, 0.f, 0.f, 0.f};
#pragma unroll 8
  for (int kk = 0; kk < kcnt; ++kk) {
    const float a = p[row][kk];
    const float4 v = *(const float4*)&vb[(size_t)kk * NV];
    acc.x = __builtin_fmaf(a, v.x, acc.x);
    acc.y = __builtin_fmaf(a, v.y, acc.y);
    acc.z = __builtin_fmaf(a, v.z, acc.z);
    acc.w = __builtin_fmaf(a, v.w, acc.w);
  }
  float* o = &out[(size_t)(b * NQ + q0 + row) * NV + vq * 128 + c4 * 4];
  atomicAdd(o + 0, acc.x);
  atomicAdd(o + 1, acc.y);
  atomicAdd(o + 2, acc.z);
  atomicAdd(o + 3, acc.w);
}

// =====================================================================
extern "C" void kernel_launch(void* const* d_in, const int* in_sizes, int n_in,
                              void* d_out, int out_size, void* d_ws, size_t ws_size,
                              hipStream_t stream) {
  const float* queries = (const float*)d_in[0];
  const float* keys    = (const float*)d_in[1];
  const float* values  = (const float*)d_in[2];
  const int*   vlens   = (const int*)d_in[3];
  const float* Wq      = (const float*)d_in[4];
  const float* Wk      = (const float*)d_in[5];
  const float* wv      = (const float*)d_in[6];
  float* out = (float*)d_out;

  char* base = (char*)d_ws;
  ushort* WtQh = (ushort*)base;                       // 256KB
  ushort* WtQl = WtQh + NH * ND;
  ushort* WtKh = WtQl + NH * ND;
  ushort* WtKl = WtKh + NH * ND;                      // ..1MB
  float*  Eq   = (float*)(base + (1 << 20));          // 1MB
  ushort* EkTb = (ushort*)(base + (2 << 20));         // 4MB
  float*  racc = (float*)(base + (6 << 20));          // 4MB
  float2* rstat = (float2*)(base + (10 << 20));       // 8KB
  // total ~10MB

  hipMemsetAsync(out, 0, (size_t)NB * NQ * NV * sizeof(float), stream);
  splitw_kernel<<<dim3(256), dim3(256), 0, stream>>>(Wq, Wk, WtQh, WtQl, WtKh, WtKl);
  proj_mfma_kernel<<<dim3(576), dim3(256), 0, stream>>>(
      queries, keys, WtQh, WtQl, WtKh, WtKl, vlens, Eq, EkTb);
  score_kernel<<<dim3(64, 4, 8), dim3(256), 0, stream>>>(Eq, EkTb, wv, vlens, racc);
  rowstats_kernel<<<dim3(256), dim3(256), 0, stream>>>(racc, vlens, rstat);
  pv_kernel<<<dim3(64, 4, 8), dim3(256), 0, stream>>>(racc, values, rstat, vlens, out);
}

// Round 4
// 179.327 us; speedup vs baseline: 1.3334x; 1.3334x over previous
//
#include <hip/hip_runtime.h>
#include <math.h>

#define NB 8
#define NQ 128
#define NK 1024
#define ND 512   // QK_DIM
#define NH 256   // HID
#define NV 512   // VDIM

typedef __attribute__((ext_vector_type(8))) short short8v;   // 8 bf16
typedef __attribute__((ext_vector_type(4))) float floatx4;

// ---------- bf16 helpers (RNE) ----------
__device__ __forceinline__ ushort f2bf(float f) {
  union { float f; unsigned u; } v; v.f = f;
  unsigned r = (v.u + 0x7FFF + ((v.u >> 16) & 1)) >> 16;
  return (ushort)r;
}
__device__ __forceinline__ float bf2f(ushort b) {
  union { unsigned u; float f; } v; v.u = ((unsigned)b) << 16;
  return v.f;
}
__device__ __forceinline__ float wave_rsum(float v) {
#pragma unroll
  for (int off = 32; off; off >>= 1) v += __shfl_xor(v, off);
  return v;
}

// =====================================================================
// K0a: W [ND][NH] f32 -> Wt hi/lo [NH][ND] bf16 (transposed + split).
// =====================================================================
__global__ __launch_bounds__(256) void splitw_kernel(
    const float* __restrict__ Wq, const float* __restrict__ Wk,
    ushort* __restrict__ WtQh, ushort* __restrict__ WtQl,
    ushort* __restrict__ WtKh, ushort* __restrict__ WtKl) {
  const int t = threadIdx.x;
  const int mat = blockIdx.x >> 7;
  const int bi = blockIdx.x & 127;            // 16 d-tiles x 8 h-tiles
  const int d0 = (bi >> 3) * 32, h0 = (bi & 7) * 32;
  const float* W = mat ? Wk : Wq;
  ushort* Oh = mat ? WtKh : WtQh;
  ushort* Ol = mat ? WtKl : WtQl;
  __shared__ float tile[32][33];
#pragma unroll
  for (int i = 0; i < 4; ++i) {
    int idx = t + 256 * i;
    int r = idx >> 5, c = idx & 31;
    tile[r][c] = W[(size_t)(d0 + r) * NH + h0 + c];
  }
  __syncthreads();
#pragma unroll
  for (int i = 0; i < 4; ++i) {
    int idx = t + 256 * i;
    int hh = idx >> 5, dd = idx & 31;
    float f = tile[dd][hh];
    ushort hi = f2bf(f);
    float lo = f - bf2f(hi);
    Oh[(size_t)(h0 + hh) * ND + d0 + dd] = hi;
    Ol[(size_t)(h0 + hh) * ND + d0 + dd] = f2bf(lo);
  }
}

// =====================================================================
// K0b: values [b][k][v] f32 -> VhT [b][v][k] bf16 (transpose, 32x32 tiles).
// k-tiles beyond ceil32(valid_len) are never read downstream -> skip.
// =====================================================================
__global__ __launch_bounds__(256) void convert_v_kernel(
    const float* __restrict__ values, const int* __restrict__ valid_lens,
    ushort* __restrict__ VhT) {
  const int b = blockIdx.z;
  const int k0 = blockIdx.x * 32;     // gridDim.x = 32
  const int v0 = blockIdx.y * 32;     // gridDim.y = 16
  const int V = valid_lens[b];
  if (k0 >= ((V + 31) & ~31)) return;  // uniform per block
  const int t = threadIdx.x;
  __shared__ float tile[32][33];
#pragma unroll
  for (int i = 0; i < 4; ++i) {
    int idx = t + 256 * i;
    int kk = idx >> 5, vv = idx & 31;   // coalesced along v
    tile[kk][vv] = values[(size_t)(b * NK + k0 + kk) * NV + v0 + vv];
  }
  __syncthreads();
#pragma unroll
  for (int i = 0; i < 4; ++i) {
    int idx = t + 256 * i;
    int vv = idx >> 5, kk = idx & 31;   // coalesced along k
    VhT[(size_t)(b * NV + v0 + vv) * NK + k0 + kk] = f2bf(tile[kk][vv]);
  }
}

// =====================================================================
// K1: projection via split-bf16 MFMA + exp(2x) epilogue (1 wave / block).
// grid (576 row-tiles, 4 col-groups), 64 threads. Row-tiles 0..63: q rows
// -> Eq f32; 64..575: k rows -> EkT[b][h][k] bf16 (tiles >= V skip).
// acc = Ahi*Whi + Ahi*Wlo + Alo*Whi  (~f32 precision).
// =====================================================================
__global__ __launch_bounds__(64) void proj_mfma_kernel(
    const float* __restrict__ queries, const float* __restrict__ keys,
    const ushort* __restrict__ WtQh, const ushort* __restrict__ WtQl,
    const ushort* __restrict__ WtKh, const ushort* __restrict__ WtKl,
    const int* __restrict__ valid_lens,
    float* __restrict__ Eq, ushort* __restrict__ EkTb) {
  const int lane = threadIdx.x;
  const int lr = lane & 15;
  const int lg = lane >> 4;
  const int bx = blockIdx.x;
  const bool isQ = bx < 64;
  const float* A;
  const ushort *Wh, *Wl;
  int arow0, b = 0, rin = 0;
  if (isQ) {
    A = queries; Wh = WtQh; Wl = WtQl; arow0 = bx * 16;
  } else {
    int kt = bx - 64;                // 0..511
    b = kt >> 6; rin = (kt & 63) * 16;
    if (rin >= valid_lens[b]) return;
    A = keys; Wh = WtKh; Wl = WtKl; arow0 = b * NK + rin;
  }
  const size_t arow = (size_t)(arow0 + lr) * ND;
  const int c0w = blockIdx.y * 64;

  floatx4 acc[4];
#pragma unroll
  for (int cf = 0; cf < 4; ++cf) acc[cf] = (floatx4){0.f, 0.f, 0.f, 0.f};

#pragma unroll 4
  for (int kk = 0; kk < 16; ++kk) {
    const int d0 = kk * 32 + lg * 8;
    float4 a0 = *(const float4*)&A[arow + d0];
    float4 a1 = *(const float4*)&A[arow + d0 + 4];
    float av[8] = {a0.x, a0.y, a0.z, a0.w, a1.x, a1.y, a1.z, a1.w};
    short8v ah, al;
#pragma unroll
    for (int j = 0; j < 8; ++j) {
      ushort h = f2bf(av[j]);
      ah[j] = (short)h;
      al[j] = (short)f2bf(av[j] - bf2f(h));
    }
#pragma unroll
    for (int cf = 0; cf < 4; ++cf) {
      const size_t wrow = (size_t)(c0w + cf * 16 + lr) * ND + d0;
      short8v bh = *(const short8v*)&Wh[wrow];
      short8v bl = *(const short8v*)&Wl[wrow];
      acc[cf] = __builtin_amdgcn_mfma_f32_16x16x32_bf16(al, bh, acc[cf], 0, 0, 0);
      acc[cf] = __builtin_amdgcn_mfma_f32_16x16x32_bf16(ah, bl, acc[cf], 0, 0, 0);
      acc[cf] = __builtin_amdgcn_mfma_f32_16x16x32_bf16(ah, bh, acc[cf], 0, 0, 0);
    }
  }

  const float C2 = 2.885390081777927f;  // 2*log2(e)
  if (isQ) {
#pragma unroll
    for (int cf = 0; cf < 4; ++cf) {
      const int h = c0w + cf * 16 + lr;
#pragma unroll
      for (int reg = 0; reg < 4; ++reg) {
        const int row = arow0 + lg * 4 + reg;
        float p = fminf(fmaxf(acc[cf][reg], -15.f), 15.f);
        Eq[(size_t)row * NH + h] = exp2f(p * C2);
      }
    }
  } else {
#pragma unroll
    for (int cf = 0; cf < 4; ++cf) {
      const int h = c0w + cf * 16 + lr;
      ushort4 e;
      e.x = f2bf(exp2f(fminf(fmaxf(acc[cf][0], -15.f), 15.f) * C2));
      e.y = f2bf(exp2f(fminf(fmaxf(acc[cf][1], -15.f), 15.f) * C2));
      e.z = f2bf(exp2f(fminf(fmaxf(acc[cf][2], -15.f), 15.f) * C2));
      e.w = f2bf(exp2f(fminf(fmaxf(acc[cf][3], -15.f), 15.f) * C2));
      *(ushort4*)&EkTb[((size_t)(b * NH + h)) * NK + rin + lg * 4] = e;
    }
  }
}

// =====================================================================
// K2: scores -> fixed-shift softmax numerators (bf16) + row sums.
// score_eff = -2*racc, racc = sum_h wv_h*rcp(1+Eq*Ek).
// Shift M = 2*SN, SN = sum_h max(-wv_h,0):  score_eff <= M always, so
// p = exp(score_eff - M) = exp2(-2log2e*(racc+SN)) in (1e-11, 1] — no max
// pass needed (softmax shift-invariance is exact).
// Writes Pb[row][k] bf16 (0 for k>=V) and atomicAdds the bf16-rounded
// row sum into rowsum[row] (f32, pre-zeroed).
// grid (64 q-pairs, 4 k-tiles, 8 b), 256 thr.
// =====================================================================
__global__ __launch_bounds__(256) void score_kernel(
    const float* __restrict__ Eq, const ushort* __restrict__ EkTb,
    const float* __restrict__ wvp, const int* __restrict__ valid_lens,
    ushort* __restrict__ Pb, float* __restrict__ rowsum) {
  const int b = blockIdx.z;
  const int V = valid_lens[b];
  const int k0 = blockIdx.y * 256;
  if (k0 >= V) return;
  const int t = threadIdx.x;
  const int q0 = blockIdx.x * 2;
  const int lane = t & 63, wid = t >> 6;
  const float L2E2 = 2.8853900817779268f;  // 2*log2(e)

  __shared__ __align__(16) float eqs[2][NH];
  __shared__ float wvs[NH];
  __shared__ float red[8];

  if (t < 128)
    ((float4*)eqs)[t] = ((const float4*)&Eq[(size_t)(b * NQ + q0) * NH])[t];
  wvs[t] = wvp[t];
  __syncthreads();

  // SN = sum_h max(-w,0) = -(sum_h min(w,0))
  float mn = wave_rsum(fminf(wvs[t], 0.f));
  if (lane == 0) red[wid] = mn;
  __syncthreads();
  const float SN = -(red[0] + red[1] + red[2] + red[3]);
  __syncthreads();

  float acc0 = 0.f, acc1 = 0.f;
  const ushort* ek = EkTb + (size_t)b * NH * NK + k0 + t;
#pragma unroll 8
  for (int h = 0; h < NH; ++h) {
    const float e = bf2f(ek[(size_t)h * NK]);
    const float w = wvs[h];
    acc0 += w * __builtin_amdgcn_rcpf(__builtin_fmaf(eqs[0][h], e, 1.f));
    acc1 += w * __builtin_amdgcn_rcpf(__builtin_fmaf(eqs[1][h], e, 1.f));
  }

  const int k = k0 + t;
  const float p0 = (k < V) ? exp2f(-L2E2 * (acc0 + SN)) : 0.f;
  const float p1 = (k < V) ? exp2f(-L2E2 * (acc1 + SN)) : 0.f;
  const ushort u0 = f2bf(p0), u1 = f2bf(p1);
  Pb[(size_t)(b * NQ + q0) * NK + k] = u0;
  Pb[(size_t)(b * NQ + q0 + 1) * NK + k] = u1;

  // row sums of the bf16-rounded p (so normalization matches PV exactly)
  float s0 = wave_rsum(bf2f(u0));
  float s1 = wave_rsum(bf2f(u1));
  if (lane == 0) { red[wid] = s0; red[4 + wid] = s1; }
  __syncthreads();
  if (t == 0) {
    atomicAdd(&rowsum[b * NQ + q0], red[0] + red[1] + red[2] + red[3]);
    atomicAdd(&rowsum[b * NQ + q0 + 1], red[4] + red[5] + red[6] + red[7]);
  }
}

// =====================================================================
// K3: PV via MFMA.  out[q][v] = (sum_k Pb[q,k]*VhT[v,k]) / rowsum[q].
// grid (8 qt, 16 vt, 8 b), 128 thr = 2 waves; wave w owns v-cols
// vt*32+w*16..+15, 16 q rows, K = ceil32(V) (Pb is 0 beyond V).
// Two accumulators break the MFMA dependency chain.
// =====================================================================
__global__ __launch_bounds__(128) void pv_mfma_kernel(
    const ushort* __restrict__ Pb, const ushort* __restrict__ VhT,
    const float* __restrict__ rowsum, const int* __restrict__ valid_lens,
    float* __restrict__ out) {
  const int w = threadIdx.x >> 6;
  const int lane = threadIdx.x & 63;
  const int lr = lane & 15, lg = lane >> 4;
  const int qt = blockIdx.x, vt = blockIdx.y, b = blockIdx.z;
  const int V = valid_lens[b];
  const int Kt = (V + 31) >> 5;
  const int q0 = qt * 16;
  const int v0 = vt * 32 + w * 16;
  const size_t prow = (size_t)(b * NQ + q0 + lr) * NK + lg * 8;
  const size_t vrow = (size_t)(b * NV + v0 + lr) * NK + lg * 8;

  floatx4 accA = (floatx4){0.f, 0.f, 0.f, 0.f};
  floatx4 accB = (floatx4){0.f, 0.f, 0.f, 0.f};
  int s = 0;
  for (; s + 2 <= Kt; s += 2) {
    short8v a0 = *(const short8v*)&Pb[prow + (size_t)s * 32];
    short8v b0 = *(const short8v*)&VhT[vrow + (size_t)s * 32];
    short8v a1 = *(const short8v*)&Pb[prow + (size_t)s * 32 + 32];
    short8v b1 = *(const short8v*)&VhT[vrow + (size_t)s * 32 + 32];
    accA = __builtin_amdgcn_mfma_f32_16x16x32_bf16(a0, b0, accA, 0, 0, 0);
    accB = __builtin_amdgcn_mfma_f32_16x16x32_bf16(a1, b1, accB, 0, 0, 0);
  }
  if (s < Kt) {
    short8v a0 = *(const short8v*)&Pb[prow + (size_t)s * 32];
    short8v b0 = *(const short8v*)&VhT[vrow + (size_t)s * 32];
    accA = __builtin_amdgcn_mfma_f32_16x16x32_bf16(a0, b0, accA, 0, 0, 0);
  }

#pragma unroll
  for (int reg = 0; reg < 4; ++reg) {
    const int row = b * NQ + q0 + lg * 4 + reg;
    const float rs = __builtin_amdgcn_rcpf(rowsum[row]);
    out[(size_t)row * NV + vt * 32 + w * 16 + lr] = (accA[reg] + accB[reg]) * rs;
  }
}

// =====================================================================
extern "C" void kernel_launch(void* const* d_in, const int* in_sizes, int n_in,
                              void* d_out, int out_size, void* d_ws, size_t ws_size,
                              hipStream_t stream) {
  const float* queries = (const float*)d_in[0];
  const float* keys    = (const float*)d_in[1];
  const float* values  = (const float*)d_in[2];
  const int*   vlens   = (const int*)d_in[3];
  const float* Wq      = (const float*)d_in[4];
  const float* Wk      = (const float*)d_in[5];
  const float* wv      = (const float*)d_in[6];
  float* out = (float*)d_out;

  char* base = (char*)d_ws;
  ushort* WtQh = (ushort*)base;                       // 4 x 256KB = 1MB
  ushort* WtQl = WtQh + NH * ND;
  ushort* WtKh = WtQl + NH * ND;
  ushort* WtKl = WtKh + NH * ND;
  float*  Eq   = (float*)(base + (1 << 20));          // 1MB
  ushort* EkTb = (ushort*)(base + (2 << 20));         // 4MB
  ushort* Pb   = (ushort*)(base + (6 << 20));         // 2MB
  ushort* VhT  = (ushort*)(base + (8 << 20));         // 8MB
  float*  rowsum = (float*)(base + (16 << 20));       // 4KB
  // total 16MB + 4KB

  hipMemsetAsync(rowsum, 0, NB * NQ * sizeof(float), stream);
  splitw_kernel<<<dim3(256), dim3(256), 0, stream>>>(Wq, Wk, WtQh, WtQl, WtKh, WtKl);
  convert_v_kernel<<<dim3(32, 16, 8), dim3(256), 0, stream>>>(values, vlens, VhT);
  proj_mfma_kernel<<<dim3(576, 4), dim3(64), 0, stream>>>(
      queries, keys, WtQh, WtQl, WtKh, WtKl, vlens, Eq, EkTb);
  score_kernel<<<dim3(64, 4, 8), dim3(256), 0, stream>>>(
      Eq, EkTb, wv, vlens, Pb, rowsum);
  pv_mfma_kernel<<<dim3(8, 16, 8), dim3(128), 0, stream>>>(
      Pb, VhT, rowsum, vlens, out);
}